// Round 6
// baseline (326.038 us; speedup 1.0000x reference)
//
#include <hip/hip_runtime.h>
#include <hip/hip_fp16.h>

// EdgeVar R6: two-axis bucket sort -> all-LDS edge pass.
//  prep:   pos -> half2 table pos16 (800KB); startg[1025] graph boundaries.
//  phaseA: bucket edges by (src/dnode, dst/dnode) into 1024 lists of 4B
//          records (sl<<13)|dl. LDS counting-sort per 4096-edge chunk,
//          wave-shuffle scan (2 barriers), coalesced segment writeout.
//  phaseB: one block per bucket; both node slices in LDS; graph id via
//          slice-local boundary search (LDS); LDS hist of sums+counts.
//          ZERO divergent global accesses per edge.
//  finalize: mean(gsum / max(gcnt,1)).
// R5 post-mortem: divergent global wave-loads cost ~2cyc/lane of per-CU
// throughput (ILP-insensitive). This removes all of them from the edge pass.

typedef int iv4 __attribute__((ext_vector_type(4)));
typedef unsigned int u32;

#define GBINS 1024
#define BUK   32
#define NBUK  1024
#define CHUNK 4096          // edges per phase-A block (8/thread @ 512)
#define MAXD  6400          // max nodes/slice: 2*6400*4B = 51.2KB LDS
#define LSSMX 512           // slice-local graph table capacity

__device__ __forceinline__ u32 divm(u32 x, unsigned long long magic) {
    return (u32)((x * magic) >> 40);    // exact floor(x/dnode) for x < 2^22
}

__global__ void prep(const float2* __restrict__ pos, const int* __restrict__ batch,
                     u32* __restrict__ pos16, int* __restrict__ startg, int N) {
    int i = blockIdx.x * blockDim.x + threadIdx.x;
    if (i >= N) return;
    float2 p = pos[i];
    __half2 h; h.x = __float2half_rn(p.x); h.y = __float2half_rn(p.y);
    u32 u; __builtin_memcpy(&u, &h, 4);
    pos16[i] = u;
    int b = batch[i];
    if (i == 0) { for (int g = 0; g <= b; ++g) startg[g] = 0; }
    else { int a = batch[i - 1]; for (int g = a + 1; g <= b; ++g) startg[g] = i; }
    if (i == N - 1) { for (int g = b + 1; g <= GBINS; ++g) startg[g] = N; }
}

// ---------------- Phase A: bucket-sort edge records ------------------------
__global__ __launch_bounds__(512)
void phaseA(const int* __restrict__ src, const int* __restrict__ dst,
            u32* __restrict__ lists, u32* __restrict__ cursors,
            int E, u32 dnode, unsigned long long magic, u32 cap) {
    __shared__ u32 cnt[NBUK];        // per-bucket count
    __shared__ u32 lofs[NBUK + 1];   // exclusive offsets into stage
    __shared__ u32 gbase[NBUK];      // global cursor base per bucket
    __shared__ u32 stage[CHUNK];     // 16KB reorder buffer
    __shared__ u32 wsum[8];
    const int tid = threadIdx.x;
    for (int i = tid; i < NBUK; i += 512) cnt[i] = 0;
    __syncthreads();

    const int base = blockIdx.x * CHUNK;
    const bool amok = ((E & 3) == 0);
    int bid[8]; u32 rank[8], rec[8];

    #pragma unroll
    for (int h = 0; h < 2; ++h) {
        const int e0 = base + h * 2048 + 4 * tid;
        iv4 sv, dv;
        const bool vec = amok && (e0 + 3 < E);
        if (vec) {
            sv = __builtin_nontemporal_load((const iv4*)(src + e0));
            dv = __builtin_nontemporal_load((const iv4*)(dst + e0));
        }
        #pragma unroll
        for (int k = 0; k < 4; ++k) {
            const int j = h * 4 + k, e = e0 + k;
            int s, d;
            if (vec)        { s = sv[k];   d = dv[k]; }
            else if (e < E) { s = src[e];  d = dst[e]; }
            else            { bid[j] = -1; continue; }
            const u32 bs = divm((u32)s, magic), bd = divm((u32)d, magic);
            const u32 sl = (u32)s - bs * dnode, dl = (u32)d - bd * dnode;
            bid[j]  = (int)(bs * BUK + bd);
            rec[j]  = (sl << 13) | dl;
            rank[j] = atomicAdd(&cnt[bid[j]], 1u);
        }
    }
    __syncthreads();

    // wave-shuffle exclusive scan of cnt[1024] (pairs: thread t owns 2t,2t+1)
    const int lane = tid & 63, wave = tid >> 6;
    const u32 a0 = cnt[2 * tid], a1 = cnt[2 * tid + 1];
    const u32 s = a0 + a1;
    u32 x = s;
    #pragma unroll
    for (int off = 1; off < 64; off <<= 1) {
        u32 n = __shfl_up(x, off, 64);
        if (lane >= off) x += n;
    }
    if (lane == 63) wsum[wave] = x;
    __syncthreads();
    if (wave == 0 && lane < 8) {
        u32 w = wsum[lane];
        #pragma unroll
        for (int off = 1; off < 8; off <<= 1) {
            u32 n = __shfl_up(w, off, 64);
            if (lane >= off) w += n;
        }
        wsum[lane] = w;
    }
    __syncthreads();
    const u32 excl = (wave ? wsum[wave - 1] : 0u) + x - s;
    lofs[2 * tid] = excl;
    lofs[2 * tid + 1] = excl + a0;
    if (tid == 511) lofs[NBUK] = excl + s;
    // reserve global space per bucket
    for (int b = tid; b < NBUK; b += 512) {
        const u32 c = cnt[b];
        gbase[b] = c ? atomicAdd(&cursors[b], c) : 0u;
    }
    __syncthreads();

    // scatter into bucket-grouped stage
    #pragma unroll
    for (int j = 0; j < 8; ++j)
        if (bid[j] >= 0) stage[lofs[bid[j]] + rank[j]] = rec[j];
    __syncthreads();

    // coalesced segment writeout (binary search bucket of position i)
    const int total = (int)lofs[NBUK];
    for (int i = tid; i < total; i += 512) {
        int b = 0;
        #pragma unroll
        for (int st = 512; st; st >>= 1)
            if (lofs[b + st] <= (u32)i) b += st;
        const u32 gpos = gbase[b] + ((u32)i - lofs[b]);
        if (gpos < cap) lists[(size_t)b * cap + gpos] = stage[i];
    }
}

// ---------------- Phase B: all-LDS edge pass -------------------------------
__global__ __launch_bounds__(512)
void phaseB(const u32* __restrict__ pos16, const int* __restrict__ startg,
            const u32* __restrict__ lists, const u32* __restrict__ cursors,
            float* __restrict__ gsum, u32* __restrict__ gcnt,
            int N, u32 dnode, u32 cap, float scale) {
    __shared__ u32 spos[MAXD];       // 25.6KB src slice (half2)
    __shared__ u32 dposA[MAXD];      // 25.6KB dst slice
    __shared__ int lss[LSSMX + 1];   // slice-local graph boundaries
    __shared__ float hs[LSSMX];      // local graph sums (only [0,span) used)
    __shared__ u32 hc[LSSMX];        // local graph counts
    __shared__ int shGb, shSpan;
    const int tid = threadIdx.x;
    const int p = blockIdx.x, bs = p >> 5, bd = p & (BUK - 1);
    const int s0 = bs * (int)dnode, d0 = bd * (int)dnode;
    const int ns = min((int)dnode, N - s0);
    const int nd = min((int)dnode, N - d0);
    for (int i = tid; i < ns; i += 512) spos[i]  = pos16[s0 + i];
    for (int i = tid; i < nd; i += 512) dposA[i] = pos16[d0 + i];
    if (tid == 0) {   // graph range [gb, ge] overlapping the src slice
        int v = s0, g = min((int)((float)v * scale), GBINS - 1);
        while (v < startg[g]) --g;
        while (v >= startg[g + 1]) ++g;
        shGb = g;
        int v2 = s0 + ns - 1, g2 = min((int)((float)v2 * scale), GBINS - 1);
        while (v2 < startg[g2]) --g2;
        while (v2 >= startg[g2 + 1]) ++g2;
        shSpan = min(g2 - g + 1, LSSMX);
    }
    __syncthreads();
    const int gb = shGb, span = shSpan;
    for (int j = tid; j < span; j += 512) { lss[j] = max(0, startg[gb + j] - s0); hs[j] = 0.f; hc[j] = 0u; }
    if (tid == 0) lss[span] = ns;
    __syncthreads();

    const u32 n = min(cursors[p], cap);
    const u32* __restrict__ lp = lists + (size_t)p * cap;
    const iv4* __restrict__ lp4 = (const iv4*)lp;
    const float jsc = (float)span / (float)ns;

    auto proc = [&](u32 r) {
        const u32 sl = r >> 13, dl = r & 8191u;
        const u32 ua = spos[sl], ub = dposA[dl];
        __half2 ha, hb;
        __builtin_memcpy(&ha, &ua, 4);
        __builtin_memcpy(&hb, &ub, 4);
        const float dx = __half2float(hb.x) - __half2float(ha.x);
        const float dy = __half2float(hb.y) - __half2float(ha.y);
        const float t  = sqrtf(fmaf(dx, dx, dy * dy)) - 1.f;
        int j = min((int)((float)sl * jsc), span - 1);
        while ((int)sl < lss[j]) --j;
        while ((int)sl >= lss[j + 1]) ++j;
        atomicAdd(&hs[j], t * t);
        atomicAdd(&hc[j], 1u);
    };

    const u32 nv4 = n >> 2;
    for (u32 q = tid; q < nv4; q += 512) {
        const iv4 rv = lp4[q];
        proc((u32)rv.x); proc((u32)rv.y); proc((u32)rv.z); proc((u32)rv.w);
    }
    for (u32 i = (nv4 << 2) + tid; i < n; i += 512) proc(lp[i]);

    __syncthreads();
    for (int j = tid; j < span; j += 512) {
        const u32 c = hc[j];
        if (c) { atomicAdd(&gsum[gb + j], hs[j]); atomicAdd(&gcnt[gb + j], c); }
    }
}

// ---------------- Fallback (proven R5 path shape, simple) -------------------
__global__ __launch_bounds__(1024)
void edge_accum_mono(const float2* __restrict__ pos, const int* __restrict__ batch,
                     const int* __restrict__ src, const int* __restrict__ dst,
                     float* __restrict__ gsum, u32* __restrict__ gcnt, int E) {
    __shared__ float ls[GBINS];
    __shared__ u32 lc[GBINS];
    for (int i = threadIdx.x; i < GBINS; i += blockDim.x) { ls[i] = 0.f; lc[i] = 0u; }
    __syncthreads();
    const int tid = blockIdx.x * blockDim.x + threadIdx.x;
    const int stride = gridDim.x * blockDim.x;
    for (int i = tid; i < E; i += stride) {
        const int s = src[i], d = dst[i];
        const float2 a = pos[s], b = pos[d];
        const int g = batch[s];
        const float dx = b.x - a.x, dy = b.y - a.y;
        const float t = sqrtf(fmaf(dx, dx, dy * dy)) - 1.f;
        atomicAdd(&ls[g], t * t);
        atomicAdd(&lc[g], 1u);
    }
    __syncthreads();
    for (int g = threadIdx.x; g < GBINS; g += blockDim.x) {
        const u32 c = lc[g];
        if (c) { atomicAdd(&gsum[g], ls[g]); atomicAdd(&gcnt[g], c); }
    }
}

__global__ void finalize_kernel(const float* __restrict__ gsum,
                                const u32* __restrict__ gcnt,
                                float* __restrict__ out,
                                const int* __restrict__ nG_ptr) {
    const int G = *nG_ptr;
    float v = 0.f;
    for (int g = threadIdx.x; g < G; g += blockDim.x)
        v += gsum[g] / fmaxf((float)gcnt[g], 1.f);
    __shared__ float w[16];
    for (int off = 32; off; off >>= 1) v += __shfl_down(v, off, 64);
    if ((threadIdx.x & 63) == 0) w[threadIdx.x >> 6] = v;
    __syncthreads();
    if (threadIdx.x == 0) {
        float s = 0.f;
        const int nw = (blockDim.x + 63) >> 6;
        for (int i = 0; i < nw; ++i) s += w[i];
        out[0] = s / (float)G;
    }
}

extern "C" void kernel_launch(void* const* d_in, const int* in_sizes, int n_in,
                              void* d_out, int out_size, void* d_ws, size_t ws_size,
                              hipStream_t stream) {
    const float2* pos   = (const float2*)d_in[0];
    const int*    ei    = (const int*)d_in[1];
    const int*    batch = (const int*)d_in[2];
    const int*    nG    = (const int*)d_in[3];

    const int N = in_sizes[0] / 2;
    const int E = in_sizes[1] / 2;
    const int* src = ei;
    const int* dst = ei + E;

    // ws: [gsum 4K][gcnt 4K][cursors 4K][startg @12K..20K][pos16 @20K][lists @1M]
    float* gsum   = (float*)d_ws;
    u32*   gcnt   = (u32*)((char*)d_ws + 4096);
    u32*   cursors= (u32*)((char*)d_ws + 8192);
    int*   startg = (int*)((char*)d_ws + 12288);
    u32*   pos16  = (u32*)((char*)d_ws + 20480);
    u32*   lists  = (u32*)((char*)d_ws + (1u << 20));
    const u32 dnode = (u32)((N + BUK - 1) / BUK);
    const u32 cap   = ((u32)(E / NBUK) + 1500u + 3u) & ~3u;   // 16B-aligned rows
    const size_t need = (1u << 20) + (size_t)NBUK * cap * 4;
    const bool fast = (dnode <= MAXD) && (ws_size >= need) &&
                      (20480 + (size_t)N * 4 <= (1u << 20)) && (N < (1 << 22));

    (void)hipMemsetAsync(d_ws, 0, 12288, stream);   // gsum + gcnt + cursors

    if (fast) {
        const unsigned long long magic = ((1ULL << 40) + dnode - 1) / dnode;
        const float scale = (float)GBINS / (float)N;
        prep<<<(N + 255) / 256, 256, 0, stream>>>(pos, batch, pos16, startg, N);
        phaseA<<<(E + CHUNK - 1) / CHUNK, 512, 0, stream>>>(
            src, dst, lists, cursors, E, dnode, magic, cap);
        phaseB<<<NBUK, 512, 0, stream>>>(
            pos16, startg, lists, cursors, gsum, gcnt, N, dnode, cap, scale);
    } else {
        edge_accum_mono<<<512, 1024, 0, stream>>>(pos, batch, src, dst, gsum, gcnt, E);
    }
    finalize_kernel<<<1, 1024, 0, stream>>>(gsum, gcnt, (float*)d_out, nG);
}

// Round 7
// 287.352 us; speedup vs baseline: 1.1346x; 1.1346x over previous
//
#include <hip/hip_runtime.h>
#include <hip/hip_fp16.h>

// EdgeVar R7: weight-folding -> 2-divergent-op main pass.
//   mean_g(S_g/C_g) == sum_e w(src_e)*t_e^2,  w(n) = 1/(G*C_batch(n)).
//   prep:    pos -> half2 table pos16; startg[1025] graph boundaries.
//   count:   per-graph edge counts (1 LDS atomic + LDS search per edge).
//   weights: rec8[n] = {half2 pos bits, 1/(G*C)} (8B, 1.6MB, L2-resident).
//   main:    per edge: gather rec8[src] + pos16[dst], acc += w*t*t in
//            REGISTERS; block-reduce; 1 global atomic per block -> d_out.
// Empirical law (R2-R6): every divergent lane-op (gather / random-LDS /
// LDS-atomic) costs ~20us per-op-per-edge per pass. Main is now at the
// 2-op floor; no binned histogram in the hot pass at all.

typedef int iv4 __attribute__((ext_vector_type(4)));
typedef unsigned int u32;

#define GBINS 1024

__device__ __forceinline__ int find_graph(int v, const int* __restrict__ ss, float scale) {
    int g = (int)((float)v * scale);
    g = min(g, GBINS - 1);
    while (v < ss[g]) --g;                 // ss[0]=0 guards bottom
    while (v >= ss[g + 1]) ++g;            // ss[GBINS]=N guards top
    return g;
}

__global__ void prep(const float2* __restrict__ pos, const int* __restrict__ batch,
                     u32* __restrict__ pos16, int* __restrict__ startg, int N) {
    int i = blockIdx.x * blockDim.x + threadIdx.x;
    if (i >= N) return;
    float2 p = pos[i];
    __half2 h; h.x = __float2half_rn(p.x); h.y = __float2half_rn(p.y);
    u32 u; __builtin_memcpy(&u, &h, 4);
    pos16[i] = u;
    int b = batch[i];
    if (i == 0) { for (int g = 0; g <= b; ++g) startg[g] = 0; }
    else { int a = batch[i - 1]; for (int g = a + 1; g <= b; ++g) startg[g] = i; }
    if (i == N - 1) { for (int g = b + 1; g <= GBINS; ++g) startg[g] = N; }
}

// ---- per-graph edge counts: 1 LDS atomic + search per edge (proven ~25-30us)
__global__ __launch_bounds__(512)
void count_kernel(const int* __restrict__ src, const int* __restrict__ startg,
                  u32* __restrict__ gcnt, int E, float scale) {
    __shared__ int ss[GBINS + 1];
    __shared__ u32 hc[GBINS];
    const int tid = threadIdx.x;
    for (int i = tid; i < GBINS + 1; i += 512) ss[i] = startg[i];
    for (int i = tid; i < GBINS; i += 512) hc[i] = 0u;
    __syncthreads();

    const int ngroups = E >> 2;
    const iv4* __restrict__ s4 = (const iv4*)src;
    const int gtid = blockIdx.x * 512 + tid, gstride = gridDim.x * 512;
    for (int i = gtid; i < ngroups; i += gstride) {
        iv4 sv = __builtin_nontemporal_load(&s4[i]);
        #pragma unroll
        for (int k = 0; k < 4; ++k)
            atomicAdd(&hc[find_graph(sv[k], ss, scale)], 1u);
    }
    for (int e = (ngroups << 2) + gtid; e < E; e += gstride)
        atomicAdd(&hc[find_graph(src[e], ss, scale)], 1u);

    __syncthreads();
    for (int j = tid; j < GBINS; j += 512) {
        const int g = (j + (blockIdx.x << 3)) & (GBINS - 1);
        const u32 c = hc[g];
        if (c) atomicAdd(&gcnt[g], c);
    }
}

// ---- rec8[n] = {pos16 bits, 1/(G*count)} ----------------------------------
__global__ void weights_kernel(const u32* __restrict__ pos16,
                               const int* __restrict__ batch,
                               const u32* __restrict__ gcnt,
                               float2* __restrict__ rec8, float invG, int N) {
    int i = blockIdx.x * blockDim.x + threadIdx.x;
    if (i >= N) return;
    const int g = batch[i];                      // coalesced; sorted -> broadcast-ish
    const float c = fmaxf((float)gcnt[g], 1.f);
    float2 r;
    r.x = __uint_as_float(pos16[i]);
    r.y = invG / c;
    rec8[i] = r;
}

// ---- main: 2 gathers + register accumulation per edge ---------------------
__global__ __launch_bounds__(512)
void main_kernel(const int* __restrict__ src, const int* __restrict__ dst,
                 const float2* __restrict__ rec8, const u32* __restrict__ pos16,
                 float* __restrict__ out, int E) {
    float acc = 0.f;
    const int ngroups = E >> 2;
    const iv4* __restrict__ s4 = (const iv4*)src;
    const iv4* __restrict__ d4 = (const iv4*)dst;
    const int gtid = blockIdx.x * 512 + threadIdx.x, gstride = gridDim.x * 512;

    for (int i = gtid; i < ngroups; i += gstride) {
        const iv4 sv = __builtin_nontemporal_load(&s4[i]);
        const iv4 dv = __builtin_nontemporal_load(&d4[i]);
        float2 ra[4]; u32 ub[4];
        #pragma unroll
        for (int k = 0; k < 4; ++k) { ra[k] = rec8[sv[k]]; ub[k] = pos16[dv[k]]; }
        #pragma unroll
        for (int k = 0; k < 4; ++k) {
            __half2 ha, hb;
            u32 uab = __float_as_uint(ra[k].x);
            __builtin_memcpy(&ha, &uab, 4);
            __builtin_memcpy(&hb, &ub[k], 4);
            const float dx = __half2float(hb.x) - __half2float(ha.x);
            const float dy = __half2float(hb.y) - __half2float(ha.y);
            const float t  = sqrtf(fmaf(dx, dx, dy * dy)) - 1.f;
            acc = fmaf(ra[k].y, t * t, acc);
        }
    }
    for (int e = (ngroups << 2) + gtid; e < E; e += gstride) {
        const float2 ra = rec8[src[e]];
        const u32 ubv = pos16[dst[e]];
        __half2 ha, hb;
        u32 uab = __float_as_uint(ra.x);
        __builtin_memcpy(&ha, &uab, 4);
        __builtin_memcpy(&hb, &ubv, 4);
        const float dx = __half2float(hb.x) - __half2float(ha.x);
        const float dy = __half2float(hb.y) - __half2float(ha.y);
        const float t  = sqrtf(fmaf(dx, dx, dy * dy)) - 1.f;
        acc = fmaf(ra.y, t * t, acc);
    }

    // block reduce -> 1 global atomic
    __shared__ float wred[8];
    const int lane = threadIdx.x & 63, wave = threadIdx.x >> 6;
    #pragma unroll
    for (int off = 32; off; off >>= 1) acc += __shfl_down(acc, off, 64);
    if (lane == 0) wred[wave] = acc;
    __syncthreads();
    if (threadIdx.x == 0) {
        float s = 0.f;
        #pragma unroll
        for (int w = 0; w < 8; ++w) s += wred[w];
        atomicAdd(out, s);
    }
}

// ---- fallback (proven R2 path) --------------------------------------------
__global__ __launch_bounds__(1024)
void edge_accum_mono(const float2* __restrict__ pos, const int* __restrict__ batch,
                     const int* __restrict__ src, const int* __restrict__ dst,
                     float* __restrict__ gsum, u32* __restrict__ gcnt, int E) {
    __shared__ float ls[GBINS];
    __shared__ u32 lc[GBINS];
    for (int i = threadIdx.x; i < GBINS; i += blockDim.x) { ls[i] = 0.f; lc[i] = 0u; }
    __syncthreads();
    const int tid = blockIdx.x * blockDim.x + threadIdx.x;
    const int stride = gridDim.x * blockDim.x;
    for (int i = tid; i < E; i += stride) {
        const int s = src[i], d = dst[i];
        const float2 a = pos[s], b = pos[d];
        const int g = batch[s];
        const float dx = b.x - a.x, dy = b.y - a.y;
        const float t = sqrtf(fmaf(dx, dx, dy * dy)) - 1.f;
        atomicAdd(&ls[g], t * t);
        atomicAdd(&lc[g], 1u);
    }
    __syncthreads();
    for (int g = threadIdx.x; g < GBINS; g += blockDim.x) {
        const u32 c = lc[g];
        if (c) { atomicAdd(&gsum[g], ls[g]); atomicAdd(&gcnt[g], c); }
    }
}

__global__ void finalize_mono(const float* __restrict__ gsum,
                              const u32* __restrict__ gcnt,
                              float* __restrict__ out,
                              const int* __restrict__ nG_ptr) {
    const int G = *nG_ptr;
    float v = 0.f;
    for (int g = threadIdx.x; g < G; g += blockDim.x)
        v += gsum[g] / fmaxf((float)gcnt[g], 1.f);
    __shared__ float w[16];
    for (int off = 32; off; off >>= 1) v += __shfl_down(v, off, 64);
    if ((threadIdx.x & 63) == 0) w[threadIdx.x >> 6] = v;
    __syncthreads();
    if (threadIdx.x == 0) {
        float s = 0.f;
        const int nw = (blockDim.x + 63) >> 6;
        for (int i = 0; i < nw; ++i) s += w[i];
        out[0] = s / (float)G;
    }
}

extern "C" void kernel_launch(void* const* d_in, const int* in_sizes, int n_in,
                              void* d_out, int out_size, void* d_ws, size_t ws_size,
                              hipStream_t stream) {
    const float2* pos   = (const float2*)d_in[0];
    const int*    ei    = (const int*)d_in[1];
    const int*    batch = (const int*)d_in[2];
    const int*    nG    = (const int*)d_in[3];

    const int N = in_sizes[0] / 2;
    const int E = in_sizes[1] / 2;
    const int* src = ei;
    const int* dst = ei + E;

    // ws: [gcnt 4K][gsum 4K (fallback)][startg @8K..16K][pos16 @16K, 4N][rec8, 8N]
    u32*   gcnt   = (u32*)d_ws;
    float* gsum   = (float*)((char*)d_ws + 4096);
    int*   startg = (int*)((char*)d_ws + 8192);
    u32*   pos16  = (u32*)((char*)d_ws + 16384);
    const size_t rec8_off = (16384 + (size_t)N * 4 + 255) & ~(size_t)255;
    float2* rec8  = (float2*)((char*)d_ws + rec8_off);
    const size_t need = rec8_off + (size_t)N * 8;
    const bool fast = (ws_size >= need) && (N >= 1);

    (void)hipMemsetAsync(d_ws, 0, 8192, stream);                      // gcnt + gsum
    (void)hipMemsetAsync(d_out, 0, out_size * sizeof(float), stream); // accumulator

    if (fast) {
        const float scale = (float)GBINS / (float)N;
        prep<<<(N + 255) / 256, 256, 0, stream>>>(pos, batch, pos16, startg, N);
        count_kernel<<<1024, 512, 0, stream>>>(src, startg, gcnt, E, scale);
        weights_kernel<<<(N + 255) / 256, 256, 0, stream>>>(
            pos16, batch, gcnt, rec8, 1.f / (float)GBINS, N);
        main_kernel<<<2048, 512, 0, stream>>>(src, dst, rec8, pos16, (float*)d_out, E);
    } else {
        edge_accum_mono<<<512, 1024, 0, stream>>>(pos, batch, src, dst, gsum, gcnt, E);
        finalize_mono<<<1, 1024, 0, stream>>>(gsum, gcnt, (float*)d_out, nG);
    }
}

// Round 8
// 253.797 us; speedup vs baseline: 1.2846x; 1.1322x over previous
//
#include <hip/hip_runtime.h>

// EdgeVar R8: R5's fused structure at minimum dispatch count.
// Post-mortems R2-R7 established:
//   - The wall is L2 random-request rate: 2E = 25.6M lane-gathers ~= 122us
//     (10.9 req/cyc/XCD ~= 0.68 random load on 16 L2 channels). Request-count
//     bound: record size (4B/8B) and ILP depth don't matter.
//   - Divergent LDS hist atomics + boundary search ride ~free on the LDS pipe
//     (R5 fused 128.5 vs R7 pure-gather 122), so counts+sums stay fused.
//   - Separate passes (R7: +30us) and bucket-sorting (R3/R6: +100us) lose.
// So: 3 dispatches. prep (startg boundaries from sorted batch + zero bins),
// fused (gather raw float2 pos, LDS hist of sums+counts, striped flush),
// finalize (mean of gsum/max(gcnt,1), direct store).

typedef int iv4 __attribute__((ext_vector_type(4)));
typedef unsigned int u32;

#define GBINS 1024

__device__ __forceinline__ int find_graph(int v, const int* __restrict__ ss, float scale) {
    int g = (int)((float)v * scale);       // ~floor(v*G/N); off by a few
    g = min(g, GBINS - 1);
    while (v < ss[g]) --g;                 // ss[0]=0 guards bottom
    while (v >= ss[g + 1]) ++g;            // ss[GBINS]=N guards top
    return g;
}

// startg[1025] from sorted batch_ids; also zeros gsum/gcnt (replaces memset).
__global__ void prep(const int* __restrict__ batch, int* __restrict__ startg,
                     float* __restrict__ gsum, u32* __restrict__ gcnt, int N) {
    const int i = blockIdx.x * blockDim.x + threadIdx.x;
    if (i < GBINS) { gsum[i] = 0.f; gcnt[i] = 0u; }
    if (i >= N) return;
    const int b = batch[i];
    if (i == 0) { for (int g = 0; g <= b; ++g) startg[g] = 0; }
    else { const int a = batch[i - 1]; for (int g = a + 1; g <= b; ++g) startg[g] = i; }
    if (i == N - 1) { for (int g = b + 1; g <= GBINS; ++g) startg[g] = N; }
}

__global__ __launch_bounds__(512)
void fused_kernel(const int* __restrict__ src, const int* __restrict__ dst,
                  const float2* __restrict__ pos, const int* __restrict__ startg,
                  float* __restrict__ gsum, u32* __restrict__ gcnt,
                  int E, float scale) {
    __shared__ int ss[GBINS + 1];
    __shared__ float hs[GBINS];
    __shared__ u32 hc[GBINS];
    const int tid = threadIdx.x;
    for (int i = tid; i < GBINS + 1; i += 512) ss[i] = startg[i];
    for (int i = tid; i < GBINS; i += 512) { hs[i] = 0.f; hc[i] = 0u; }
    __syncthreads();

    const int ngroups = E >> 2;            // 4 edges/thread/iter
    const iv4* __restrict__ s4 = (const iv4*)src;
    const iv4* __restrict__ d4 = (const iv4*)dst;
    const int gtid = blockIdx.x * 512 + tid, gstride = gridDim.x * 512;

    for (int i = gtid; i < ngroups; i += gstride) {
        const iv4 sv = __builtin_nontemporal_load(&s4[i]);
        const iv4 dv = __builtin_nontemporal_load(&d4[i]);
        float2 pa[4], pb[4];
        #pragma unroll
        for (int k = 0; k < 4; ++k) { pa[k] = pos[sv[k]]; pb[k] = pos[dv[k]]; }
        #pragma unroll
        for (int k = 0; k < 4; ++k) {
            const float dx = pb[k].x - pa[k].x;
            const float dy = pb[k].y - pa[k].y;
            const float t  = sqrtf(fmaf(dx, dx, dy * dy)) - 1.f;
            const int g = find_graph(sv[k], ss, scale);
            atomicAdd(&hs[g], t * t);      // LDS pipe: ~free under the L2 wall
            atomicAdd(&hc[g], 1u);
        }
    }
    for (int e = (ngroups << 2) + gtid; e < E; e += gstride) {   // tail
        const int s = src[e], d = dst[e];
        const float2 a = pos[s], b = pos[d];
        const float dx = b.x - a.x, dy = b.y - a.y;
        const float t  = sqrtf(fmaf(dx, dx, dy * dy)) - 1.f;
        const int g = find_graph(s, ss, scale);
        atomicAdd(&hs[g], t * t);
        atomicAdd(&hc[g], 1u);
    }

    __syncthreads();
    // striped flush: rotate bin order per block to spread same-address bursts
    for (int j = tid; j < GBINS; j += 512) {
        const int g = (j + (blockIdx.x << 3)) & (GBINS - 1);
        const u32 c = hc[g];
        if (c) { atomicAdd(&gcnt[g], c); atomicAdd(&gsum[g], hs[g]); }
    }
}

__global__ void finalize_kernel(const float* __restrict__ gsum,
                                const u32* __restrict__ gcnt,
                                float* __restrict__ out,
                                const int* __restrict__ nG_ptr) {
    const int G = *nG_ptr;
    float v = 0.f;
    for (int g = threadIdx.x; g < G; g += blockDim.x)
        v += gsum[g] / fmaxf((float)gcnt[g], 1.f);
    __shared__ float w[16];
    for (int off = 32; off; off >>= 1) v += __shfl_down(v, off, 64);
    if ((threadIdx.x & 63) == 0) w[threadIdx.x >> 6] = v;
    __syncthreads();
    if (threadIdx.x == 0) {
        float s = 0.f;
        const int nw = (blockDim.x + 63) >> 6;
        for (int i = 0; i < nw; ++i) s += w[i];
        out[0] = s / (float)G;             // direct store: no d_out memset needed
    }
}

extern "C" void kernel_launch(void* const* d_in, const int* in_sizes, int n_in,
                              void* d_out, int out_size, void* d_ws, size_t ws_size,
                              hipStream_t stream) {
    const float2* pos   = (const float2*)d_in[0];
    const int*    ei    = (const int*)d_in[1];
    const int*    batch = (const int*)d_in[2];
    const int*    nG    = (const int*)d_in[3];

    const int N = in_sizes[0] / 2;
    const int E = in_sizes[1] / 2;
    const int* src = ei;
    const int* dst = ei + E;

    // ws: [gsum 4K][gcnt 4K][startg 1025 ints]
    float* gsum   = (float*)d_ws;
    u32*   gcnt   = (u32*)((char*)d_ws + 4096);
    int*   startg = (int*)((char*)d_ws + 8192);

    const float scale = (float)GBINS / (float)N;
    prep<<<(N + 255) / 256, 256, 0, stream>>>(batch, startg, gsum, gcnt, N);
    fused_kernel<<<1024, 512, 0, stream>>>(src, dst, pos, startg, gsum, gcnt, E, scale);
    finalize_kernel<<<1, 1024, 0, stream>>>(gsum, gcnt, (float*)d_out, nG);
}